// Round 2
// 210.289 us; speedup vs baseline: 1.0172x; 1.0172x over previous
//
#include <hip/hip_runtime.h>
#include <hip/hip_bf16.h>

// Problem constants
#define BATCH 8
#define CCH   256
#define NPOS  4096
#define CQK   32

typedef __attribute__((ext_vector_type(8))) short short8;   // 8 bf16 = 4 VGPRs (MFMA A/B frag)
typedef __attribute__((ext_vector_type(4))) float f32x4;    // MFMA C/D frag

__device__ inline unsigned short f2b(float f) {
    __hip_bfloat16 h = __float2bfloat16(f);
    return *reinterpret_cast<unsigned short*>(&h);
}

// ---------------------------------------------------------------------------
// Fragment-block swizzled layouts.  A 512-short block holds one 16x32 MFMA
// operand tile; lane (q=quad, ln) reads short8 at block*512 + (q*16+ln)*8.
//   qb/kb: qk_addr  — [b][n>>4][c>>3][n&15][c&7]           (c < 32)
//   vb:     v_addr  — [b][j>>5][c>>4][(j>>3)&3][c&15][j&7]
//   wsw:    wsw_addr — og-unit = 16 rows x 256 c; og: q=0..1,k=2..3,v=4..19,f=20..35
// ---------------------------------------------------------------------------
__device__ inline size_t qk_addr(int b, int n, int c) {
    return ((((size_t)b * 256 + (n >> 4)) * 4 + (c >> 3)) * 16 + (n & 15)) * 8 + (c & 7);
}
__device__ inline size_t v_addr(int b, int c, int j) {
    return (((((size_t)b * 128 + (j >> 5)) * 16 + (c >> 4)) * 4 + ((j >> 3) & 3)) * 16 + (c & 15)) * 8 + (j & 7);
}
__device__ inline size_t wsw_addr(int og, int c, int ol) {
    return ((size_t)(og * 8 + (c >> 5))) * 512 + (((c >> 3) & 3) * 16 + ol) * 8 + (c & 7);
}

// ---------------------------------------------------------------------------
// Kernel 0: prep_w — weights fp32 -> wsw bf16 fragment layout (36 og units).
// (x-transpose is now fused into qkv_kernel; xt is gone.)
// ---------------------------------------------------------------------------
__global__ __launch_bounds__(256, 4)
void prep_w_kernel(const float* __restrict__ Wq, const float* __restrict__ Wk,
                   const float* __restrict__ Wv, const float* __restrict__ Wf,
                   unsigned short* __restrict__ wsw)
{
    const int og = blockIdx.x;           // 0..35
    const int t  = threadIdx.x;
    const float* src; int orow;
    if (og < 2)       { src = Wq; orow = og * 16; }
    else if (og < 4)  { src = Wk; orow = (og - 2) * 16; }
    else if (og < 20) { src = Wv; orow = (og - 4) * 16; }
    else              { src = Wf; orow = (og - 20) * 16; }
    #pragma unroll
    for (int e = 0; e < 16; ++e) {
        int idx = t + e * 256;
        int ol = idx >> 8, c = idx & 255;
        wsw[wsw_addr(og, c, ol)] = f2b(src[(orow + ol) * 256 + c]);
    }
}

// ---------------------------------------------------------------------------
// Kernel 1: fused transpose + QKV projection.
// One block per (nt, b).  Each wave builds the x^T bf16 fragments for its own
// 16-position subtile (scalar fp32 loads: 16 lanes x 4B = full 64B sectors per
// quad), shares all 32 fragments through LDS, then computes:
//   waves 0/1: q cols 0..31, waves 2/3: k cols 0..31  (weights as A-operand)
//   every wave: v o-chunk w*64..w*64+63                (weights as B-operand)
// A-frag and B-frag lane layouts are identical for 16x16x32, so one fragment
// set serves both roles.  Same MFMA k-chain order as the old path -> outputs
// are bit-identical.  Kills the xt round-trip (16.8MB write + ~67MB read).
// ---------------------------------------------------------------------------
__global__ __launch_bounds__(256, 2)
void qkv_kernel(const float* __restrict__ x,
                const unsigned short* __restrict__ wsw,
                const float* __restrict__ bq, const float* __restrict__ bk,
                const float* __restrict__ bv,
                unsigned short* __restrict__ qb, unsigned short* __restrict__ kb,
                unsigned short* __restrict__ vb)
{
    __shared__ __align__(16) unsigned short xfrag[4][8][512];   // [n-subtile][kk][lane*8] = 32KB

    const int nt   = blockIdx.x;          // 64 position tiles
    const int b    = blockIdx.y;
    const int t    = threadIdx.x;
    const int w    = t >> 6;
    const int lane = t & 63;
    const int q    = lane >> 4;
    const int ln   = lane & 15;
    const int lofs = (q * 16 + ln) * 8;

    // ---- build x^T fragments for n-subtile it == w ----
    {
        const float* xb = x + ((size_t)b * 256) * 4096 + (nt * 64 + w * 16 + ln);
        #pragma unroll
        for (int kk = 0; kk < 8; ++kk) {
            short8 s;
            #pragma unroll
            for (int j = 0; j < 8; ++j)
                ((unsigned short*)&s)[j] = f2b(xb[(size_t)(kk * 32 + q * 8 + j) * 4096]);
            *(short8*)&xfrag[w][kk][lane * 8] = s;
        }
    }
    __syncthreads();

    // ---- q/k weight fragments (og = w) + bias ----
    short8 wqk[8];
    #pragma unroll
    for (int kk = 0; kk < 8; ++kk)
        wqk[kk] = *(const short8*)(wsw + (size_t)(w * 8 + kk) * 512 + lofs);
    const float* bias = (w < 2) ? bq : bk;
    const int cb16 = (w & 1) * 16;
    const float b0 = bias[cb16 + q * 4 + 0];
    const float b1 = bias[cb16 + q * 4 + 1];
    const float b2 = bias[cb16 + q * 4 + 2];
    const float b3 = bias[cb16 + q * 4 + 3];
    unsigned short* dst = (w < 2) ? qb : kb;

    #pragma unroll
    for (int it = 0; it < 4; ++it) {
        short8 xf[8];
        #pragma unroll
        for (int kk = 0; kk < 8; ++kk)
            xf[kk] = *(const short8*)&xfrag[it][kk][lane * 8];

        // ---- q/k: D[o-rows][n-cols] ----
        {
            f32x4 acc = {b0, b1, b2, b3};
            #pragma unroll
            for (int kk = 0; kk < 8; ++kk)
                acc = __builtin_amdgcn_mfma_f32_16x16x32_bf16(wqk[kk], xf[kk], acc, 0, 0, 0);
            ushort4 s = {f2b(acc[0]), f2b(acc[1]), f2b(acc[2]), f2b(acc[3])};
            *(ushort4*)(dst + qk_addr(b, nt * 64 + it * 16 + ln, cb16 + q * 4)) = s;
        }

        // ---- v: D[j-rows][c-cols], o-chunk w*64 ----
        #pragma unroll
        for (int oq = 0; oq < 4; ++oq) {
            const int c  = w * 64 + oq * 16 + ln;
            const float bb = bv[c];
            f32x4 acc = {bb, bb, bb, bb};
            const int og = 4 + w * 4 + oq;
            #pragma unroll
            for (int kk = 0; kk < 8; ++kk) {
                short8 bfr = *(const short8*)(wsw + (size_t)(og * 8 + kk) * 512 + lofs);
                acc = __builtin_amdgcn_mfma_f32_16x16x32_bf16(xf[kk], bfr, acc, 0, 0, 0);
            }
            ushort4 s = {f2b(acc[0]), f2b(acc[1]), f2b(acc[2]), f2b(acc[3])};
            *(ushort4*)(vb + v_addr(b, c, nt * 64 + it * 16 + q * 4)) = s;
        }
    }
}

// ---------------------------------------------------------------------------
// Kernel 2: fused flash attention + output projection.
// Main loop is the verified R8 pipeline (K/V register prefetch, unchanged).
// Epilogue: normalized O (bf16) -> LDS (aliases the dead P buffer), barrier,
// then each wave computes its o-chunk of out = Wf * O_n + bf with 128 MFMAs,
// storing fp32 directly.  Kills the obb round-trip and the proj kernel.
// ---------------------------------------------------------------------------
__global__ __launch_bounds__(256, 2)
void attn_kernel(const unsigned short* __restrict__ qb,
                 const unsigned short* __restrict__ kb,
                 const unsigned short* __restrict__ vb,
                 const unsigned short* __restrict__ wsw,
                 const float* __restrict__ bfb, float* __restrict__ out)
{
    // shbuf aliases: main loop P tiles [2][64][72] (9216 shorts),
    //                epilogue O_n      [64][264]   (16896 shorts)
    __shared__ __align__(16) unsigned short shbuf[64 * 264];
    __shared__ float lred[64];

    const int bid  = blockIdx.x;
    const int b    = bid & 7;                    // XCD swizzle
    const int i0   = (bid >> 3) * 64;
    const int t    = threadIdx.x;
    const int w    = t >> 6;
    const int lane = t & 63;
    const int quad = lane >> 4;
    const int ln   = lane & 15;

    const int ibase = i0 + w * 16;
    const int lofs  = (quad * 16 + ln) * 8;

    const short8 qfrag = *(const short8*)(qb + (((size_t)b * 256 + (ibase >> 4)) * 512) + lofs);

    f32x4 acc[4][4];                             // [i-tile][c-chunk]
    #pragma unroll
    for (int it = 0; it < 4; ++it)
        #pragma unroll
        for (int cc = 0; cc < 4; ++cc) acc[it][cc] = (f32x4){0.f, 0.f, 0.f, 0.f};
    float accl[4] = {0.f, 0.f, 0.f, 0.f};

    const unsigned short* kbase = kb + (size_t)b * 256 * 512;
    const unsigned short* vbase = vb + (size_t)b * 128 * 8192;

    // ---- prologue: prefetch j0 = 0 fragments ----
    short8 kf[4], vf[4][2];
    #pragma unroll
    for (int jc = 0; jc < 4; ++jc)
        kf[jc] = *(const short8*)(kbase + (size_t)jc * 512 + lofs);
    #pragma unroll
    for (int cc = 0; cc < 4; ++cc) {
        vf[cc][0] = *(const short8*)(vbase + (w * 4 + cc) * 512 + lofs);
        vf[cc][1] = *(const short8*)(vbase + 8192 + (w * 4 + cc) * 512 + lofs);
    }

    int pb = 0;
    for (int j0 = 0; j0 < 4096; j0 += 64, pb ^= 1) {
        // ---- issue next iteration's K/V loads first (wrap at the end) ----
        const int jn = (j0 + 64) & 4095;
        short8 kf_n[4], vf_n[4][2];
        #pragma unroll
        for (int jc = 0; jc < 4; ++jc)
            kf_n[jc] = *(const short8*)(kbase + ((size_t)((jn >> 4) + jc) * 512) + lofs);
        const unsigned short* vt_n = vbase + (size_t)(jn >> 5) * 8192;
        #pragma unroll
        for (int cc = 0; cc < 4; ++cc) {
            vf_n[cc][0] = *(const short8*)(vt_n + (w * 4 + cc) * 512 + lofs);
            vf_n[cc][1] = *(const short8*)(vt_n + 8192 + (w * 4 + cc) * 512 + lofs);
        }
        // ---- S = Q K^T with resident K ----
        f32x4 s[4];
        #pragma unroll
        for (int jc = 0; jc < 4; ++jc)
            s[jc] = __builtin_amdgcn_mfma_f32_16x16x32_bf16(qfrag, kf[jc],
                     (f32x4){0.f, 0.f, 0.f, 0.f}, 0, 0, 0);
        // ---- P = exp(S); row sums; write block-shared P (C-layout) ----
        #pragma unroll
        for (int jc = 0; jc < 4; ++jc) {
            #pragma unroll
            for (int r = 0; r < 4; ++r) {
                float p = __expf(s[jc][r]);
                accl[r] += p;
                shbuf[((size_t)(pb * 64 + w * 16 + quad * 4 + r)) * 72 + jc * 16 + ln] = f2b(p);
            }
        }
        __syncthreads();
        // ---- O += P V with resident V : 32 MFMAs ----
        #pragma unroll
        for (int it = 0; it < 4; ++it) {
            const short8 pf0 = *(const short8*)&shbuf[((size_t)(pb * 64 + it * 16 + ln)) * 72 + quad * 8];
            const short8 pf1 = *(const short8*)&shbuf[((size_t)(pb * 64 + it * 16 + ln)) * 72 + 32 + quad * 8];
            #pragma unroll
            for (int cc = 0; cc < 4; ++cc) {
                acc[it][cc] = __builtin_amdgcn_mfma_f32_16x16x32_bf16(pf0, vf[cc][0], acc[it][cc], 0, 0, 0);
                acc[it][cc] = __builtin_amdgcn_mfma_f32_16x16x32_bf16(pf1, vf[cc][1], acc[it][cc], 0, 0, 0);
            }
        }
        // ---- rotate prefetched fragments ----
        #pragma unroll
        for (int jc = 0; jc < 4; ++jc) kf[jc] = kf_n[jc];
        #pragma unroll
        for (int cc = 0; cc < 4; ++cc) {
            vf[cc][0] = vf_n[cc][0];
            vf[cc][1] = vf_n[cc][1];
        }
    }

    #pragma unroll
    for (int r = 0; r < 4; ++r) {
        float v = accl[r];
        v += __shfl_xor(v, 1, 16);
        v += __shfl_xor(v, 2, 16);
        v += __shfl_xor(v, 4, 16);
        v += __shfl_xor(v, 8, 16);
        if (ln == 0) lred[w * 16 + quad * 4 + r] = v;
    }
    __syncthreads();   // also orders: last P reads before O_n overwrites shbuf

    // ---- epilogue A: normalize O, write bf16 to LDS [i][c] (stride 264) ----
    #pragma unroll
    for (int it = 0; it < 4; ++it) {
        float linv[4];
        #pragma unroll
        for (int r = 0; r < 4; ++r) linv[r] = 1.f / lred[it * 16 + quad * 4 + r];
        #pragma unroll
        for (int cc = 0; cc < 4; ++cc) {
            const int c = w * 64 + cc * 16 + ln;
            #pragma unroll
            for (int r = 0; r < 4; ++r)
                shbuf[((size_t)(it * 16 + quad * 4 + r)) * 264 + c] = f2b(acc[it][cc][r] * linv[r]);
        }
    }
    __syncthreads();

    // ---- epilogue B: out = Wf * O_n + bf, each wave owns o-chunk w*64 ----
    #pragma unroll
    for (int it = 0; it < 4; ++it) {
        short8 af[8];
        #pragma unroll
        for (int kk = 0; kk < 8; ++kk)
            af[kk] = *(const short8*)&shbuf[((size_t)(it * 16 + ln)) * 264 + kk * 32 + quad * 8];
        #pragma unroll
        for (int oq = 0; oq < 4; ++oq) {
            const int o  = w * 64 + oq * 16 + ln;
            const int og = 20 + w * 4 + oq;
            f32x4 pa = {0.f, 0.f, 0.f, 0.f};
            #pragma unroll
            for (int kk = 0; kk < 8; ++kk) {
                short8 bfr = *(const short8*)(wsw + (size_t)(og * 8 + kk) * 512 + lofs);
                pa = __builtin_amdgcn_mfma_f32_16x16x32_bf16(af[kk], bfr, pa, 0, 0, 0);
            }
            const float bias = bfb[o];
            float4 s = {pa[0] + bias, pa[1] + bias, pa[2] + bias, pa[3] + bias};
            *(float4*)(out + (size_t)(b * 256 + o) * 4096 + i0 + it * 16 + quad * 4) = s;
        }
    }
}

// ---------------------------------------------------------------------------
extern "C" void kernel_launch(void* const* d_in, const int* in_sizes, int n_in,
                              void* d_out, int out_size, void* d_ws, size_t ws_size,
                              hipStream_t stream)
{
    const float* x  = (const float*)d_in[0];
    const float* Wq = (const float*)d_in[1];
    const float* bq = (const float*)d_in[2];
    const float* Wk = (const float*)d_in[3];
    const float* bk = (const float*)d_in[4];
    const float* Wv = (const float*)d_in[5];
    const float* bv = (const float*)d_in[6];
    const float* Wf = (const float*)d_in[7];
    const float* bf = (const float*)d_in[8];
    float* out = (float*)d_out;

    // workspace (shorts): qb, kb, vb, wsw  (xt/obb eliminated by fusion)
    unsigned short* qb  = (unsigned short*)d_ws;                  // 8*4096*32
    unsigned short* kb  = qb + (size_t)BATCH * NPOS * CQK;
    unsigned short* vb  = kb + (size_t)BATCH * NPOS * CQK;        // 8*256*4096
    unsigned short* wsw = vb + (size_t)BATCH * CCH * NPOS;        // 36*8*512

    prep_w_kernel<<<36, 256, 0, stream>>>(Wq, Wk, Wv, Wf, wsw);
    qkv_kernel<<<dim3(64, 8), 256, 0, stream>>>(x, wsw, bq, bk, bv, qb, kb, vb);
    attn_kernel<<<512, 256, 0, stream>>>(qb, kb, vb, wsw, bf, out);
}

// Round 3
// 204.687 us; speedup vs baseline: 1.0450x; 1.0274x over previous
//
#include <hip/hip_runtime.h>
#include <hip/hip_bf16.h>

// Problem constants
#define BATCH 8
#define CCH   256
#define NPOS  4096
#define CQK   32

typedef __attribute__((ext_vector_type(8))) short short8;   // 8 bf16 = 4 VGPRs (MFMA A/B frag)
typedef __attribute__((ext_vector_type(4))) float f32x4;    // MFMA C/D frag

__device__ inline unsigned short f2b(float f) {
    __hip_bfloat16 h = __float2bfloat16(f);
    return *reinterpret_cast<unsigned short*>(&h);
}

// ---------------------------------------------------------------------------
// Fragment-block swizzled layouts.  A 512-short block holds one 16x32 MFMA
// operand tile; lane (q=quad, ln) reads short8 at block*512 + (q*16+ln)*8.
//   qb/kb: qk_addr  — [b][n>>4][c>>3][n&15][c&7]           (c < 32)
//   vb:     v_addr  — [b][j>>5][c>>4][(j>>3)&3][c&15][j&7]
//   wsw:    wsw_addr — og-unit = 16 rows x 256 c; og: q=0..1,k=2..3,v=4..19,f=20..35
// ---------------------------------------------------------------------------
__device__ inline size_t qk_addr(int b, int n, int c) {
    return ((((size_t)b * 256 + (n >> 4)) * 4 + (c >> 3)) * 16 + (n & 15)) * 8 + (c & 7);
}
__device__ inline size_t v_addr(int b, int c, int j) {
    return (((((size_t)b * 128 + (j >> 5)) * 16 + (c >> 4)) * 4 + ((j >> 3) & 3)) * 16 + (c & 15)) * 8 + (j & 7);
}
__device__ inline size_t wsw_addr(int og, int c, int ol) {
    return ((size_t)(og * 8 + (c >> 5))) * 512 + (((c >> 3) & 3) * 16 + ol) * 8 + (c & 7);
}

// ---------------------------------------------------------------------------
// Kernel 0: prep_w — weights fp32 -> wsw bf16 fragment layout (36 og units).
// ---------------------------------------------------------------------------
__global__ __launch_bounds__(256, 4)
void prep_w_kernel(const float* __restrict__ Wq, const float* __restrict__ Wk,
                   const float* __restrict__ Wv, const float* __restrict__ Wf,
                   unsigned short* __restrict__ wsw)
{
    const int og = blockIdx.x;           // 0..35
    const int t  = threadIdx.x;
    const float* src; int orow;
    if (og < 2)       { src = Wq; orow = og * 16; }
    else if (og < 4)  { src = Wk; orow = (og - 2) * 16; }
    else if (og < 20) { src = Wv; orow = (og - 4) * 16; }
    else              { src = Wf; orow = (og - 20) * 16; }
    #pragma unroll
    for (int e = 0; e < 16; ++e) {
        int idx = t + e * 256;
        int ol = idx >> 8, c = idx & 255;
        wsw[wsw_addr(og, c, ol)] = f2b(src[(orow + ol) * 256 + c]);
    }
}

// ---------------------------------------------------------------------------
// Kernel 1: fused transpose + QKV projection — R3: vectorized load path.
// R2's 64 scalar fp32 global loads/thread at 2 blocks/CU was latency-bound
// (~100 µs vs ~10 µs roofline).  Now: float4-coalesced global loads (16/thr)
// -> bf16 LDS [c][n] pad-2 (frag reads hit all 32 banks at 2 lanes each =
// conflict-free) -> fragments via cheap scalar ds_read.  3 blocks/CU.
// Same f2b rounding + MFMA chain order -> outputs bit-identical to R2.
// ---------------------------------------------------------------------------
__global__ __launch_bounds__(256, 3)
void qkv_kernel(const float* __restrict__ x,
                const unsigned short* __restrict__ wsw,
                const float* __restrict__ bq, const float* __restrict__ bk,
                const float* __restrict__ bv,
                unsigned short* __restrict__ qb, unsigned short* __restrict__ kb,
                unsigned short* __restrict__ vb)
{
    __shared__ __align__(16) unsigned short xl[256 * 66];   // [c][n+2 pad] bf16, 33792 B

    const int nt   = blockIdx.x;          // 64 position tiles
    const int b    = blockIdx.y;
    const int t    = threadIdx.x;
    const int w    = t >> 6;
    const int lane = t & 63;
    const int q    = lane >> 4;
    const int ln   = lane & 15;
    const int lofs = (q * 16 + ln) * 8;

    // ---- stage x tile [256c x 64n] -> bf16 LDS, fully coalesced ----
    {
        const float* xb = x + ((size_t)b * 256) * 4096 + nt * 64;
        #pragma unroll
        for (int e = 0; e < 16; ++e) {
            const int g  = e * 256 + t;        // 0..4095
            const int c  = g >> 4;
            const int nq = (g & 15) * 4;
            float4 v = *(const float4*)(xb + (size_t)c * 4096 + nq);
            ushort4 s4 = {f2b(v.x), f2b(v.y), f2b(v.z), f2b(v.w)};
            *(ushort4*)&xl[c * 66 + nq] = s4;
        }
    }
    __syncthreads();

    // ---- q/k weight fragments (og = w) + bias ----
    short8 wqk[8];
    #pragma unroll
    for (int kk = 0; kk < 8; ++kk)
        wqk[kk] = *(const short8*)(wsw + (size_t)(w * 8 + kk) * 512 + lofs);
    const float* bias = (w < 2) ? bq : bk;
    const int cb16 = (w & 1) * 16;
    const float b0 = bias[cb16 + q * 4 + 0];
    const float b1 = bias[cb16 + q * 4 + 1];
    const float b2 = bias[cb16 + q * 4 + 2];
    const float b3 = bias[cb16 + q * 4 + 3];
    unsigned short* dst = (w < 2) ? qb : kb;

    #pragma unroll
    for (int it = 0; it < 4; ++it) {
        // ---- build x^T fragments from LDS (conflict-free: bank = 8q+ln/2) ----
        short8 xf[8];
        #pragma unroll
        for (int kk = 0; kk < 8; ++kk) {
            short8 s;
            #pragma unroll
            for (int j = 0; j < 8; ++j)
                ((unsigned short*)&s)[j] = xl[(kk * 32 + q * 8 + j) * 66 + it * 16 + ln];
            xf[kk] = s;
        }

        // ---- q/k: D[o-rows][n-cols] ----
        {
            f32x4 acc = {b0, b1, b2, b3};
            #pragma unroll
            for (int kk = 0; kk < 8; ++kk)
                acc = __builtin_amdgcn_mfma_f32_16x16x32_bf16(wqk[kk], xf[kk], acc, 0, 0, 0);
            ushort4 s = {f2b(acc[0]), f2b(acc[1]), f2b(acc[2]), f2b(acc[3])};
            *(ushort4*)(dst + qk_addr(b, nt * 64 + it * 16 + ln, cb16 + q * 4)) = s;
        }

        // ---- v: D[j-rows][c-cols], o-chunk w*64 ----
        #pragma unroll
        for (int oq = 0; oq < 4; ++oq) {
            const int c  = w * 64 + oq * 16 + ln;
            const float bb = bv[c];
            f32x4 acc = {bb, bb, bb, bb};
            const int og = 4 + w * 4 + oq;
            #pragma unroll
            for (int kk = 0; kk < 8; ++kk) {
                short8 bfr = *(const short8*)(wsw + (size_t)(og * 8 + kk) * 512 + lofs);
                acc = __builtin_amdgcn_mfma_f32_16x16x32_bf16(xf[kk], bfr, acc, 0, 0, 0);
            }
            ushort4 s = {f2b(acc[0]), f2b(acc[1]), f2b(acc[2]), f2b(acc[3])};
            *(ushort4*)(vb + v_addr(b, c, nt * 64 + it * 16 + q * 4)) = s;
        }
    }
}

// ---------------------------------------------------------------------------
// Kernel 2: fused flash attention + output projection.
// R3: P-tile LDS stride 72 -> 70 shorts.  At 72, pf0/pf1 ds_read_b128 banks
// = 4*(ln+quad) mod 32 -> 8 distinct banks = 8-way conflict (the 4.46M
// SQ_LDS_BANK_CONFLICT).  At 70: bank = 3*ln+4*quad -> ~2 lanes/bank = free.
// Epilogue O_n stride 264 -> 266 for the same reason (af reads were 8-way).
// ---------------------------------------------------------------------------
__global__ __launch_bounds__(256, 2)
void attn_kernel(const unsigned short* __restrict__ qb,
                 const unsigned short* __restrict__ kb,
                 const unsigned short* __restrict__ vb,
                 const unsigned short* __restrict__ wsw,
                 const float* __restrict__ bfb, float* __restrict__ out)
{
    // shbuf aliases: main loop P tiles [2][64][70] (8960 shorts),
    //                epilogue O_n      [64][266]   (17024 shorts)
    __shared__ __align__(16) unsigned short shbuf[64 * 266];
    __shared__ float lred[64];

    const int bid  = blockIdx.x;
    const int b    = bid & 7;                    // XCD swizzle
    const int i0   = (bid >> 3) * 64;
    const int t    = threadIdx.x;
    const int w    = t >> 6;
    const int lane = t & 63;
    const int quad = lane >> 4;
    const int ln   = lane & 15;

    const int ibase = i0 + w * 16;
    const int lofs  = (quad * 16 + ln) * 8;

    const short8 qfrag = *(const short8*)(qb + (((size_t)b * 256 + (ibase >> 4)) * 512) + lofs);

    f32x4 acc[4][4];                             // [i-tile][c-chunk]
    #pragma unroll
    for (int it = 0; it < 4; ++it)
        #pragma unroll
        for (int cc = 0; cc < 4; ++cc) acc[it][cc] = (f32x4){0.f, 0.f, 0.f, 0.f};
    float accl[4] = {0.f, 0.f, 0.f, 0.f};

    const unsigned short* kbase = kb + (size_t)b * 256 * 512;
    const unsigned short* vbase = vb + (size_t)b * 128 * 8192;

    // ---- prologue: prefetch j0 = 0 fragments ----
    short8 kf[4], vf[4][2];
    #pragma unroll
    for (int jc = 0; jc < 4; ++jc)
        kf[jc] = *(const short8*)(kbase + (size_t)jc * 512 + lofs);
    #pragma unroll
    for (int cc = 0; cc < 4; ++cc) {
        vf[cc][0] = *(const short8*)(vbase + (w * 4 + cc) * 512 + lofs);
        vf[cc][1] = *(const short8*)(vbase + 8192 + (w * 4 + cc) * 512 + lofs);
    }

    int pb = 0;
    for (int j0 = 0; j0 < 4096; j0 += 64, pb ^= 1) {
        // ---- issue next iteration's K/V loads first (wrap at the end) ----
        const int jn = (j0 + 64) & 4095;
        short8 kf_n[4], vf_n[4][2];
        #pragma unroll
        for (int jc = 0; jc < 4; ++jc)
            kf_n[jc] = *(const short8*)(kbase + ((size_t)((jn >> 4) + jc) * 512) + lofs);
        const unsigned short* vt_n = vbase + (size_t)(jn >> 5) * 8192;
        #pragma unroll
        for (int cc = 0; cc < 4; ++cc) {
            vf_n[cc][0] = *(const short8*)(vt_n + (w * 4 + cc) * 512 + lofs);
            vf_n[cc][1] = *(const short8*)(vt_n + 8192 + (w * 4 + cc) * 512 + lofs);
        }
        // ---- S = Q K^T with resident K ----
        f32x4 s[4];
        #pragma unroll
        for (int jc = 0; jc < 4; ++jc)
            s[jc] = __builtin_amdgcn_mfma_f32_16x16x32_bf16(qfrag, kf[jc],
                     (f32x4){0.f, 0.f, 0.f, 0.f}, 0, 0, 0);
        // ---- P = exp(S); row sums; write block-shared P (C-layout) ----
        #pragma unroll
        for (int jc = 0; jc < 4; ++jc) {
            #pragma unroll
            for (int r = 0; r < 4; ++r) {
                float p = __expf(s[jc][r]);
                accl[r] += p;
                shbuf[((size_t)(pb * 64 + w * 16 + quad * 4 + r)) * 70 + jc * 16 + ln] = f2b(p);
            }
        }
        __syncthreads();
        // ---- O += P V with resident V : 32 MFMAs ----
        #pragma unroll
        for (int it = 0; it < 4; ++it) {
            const short8 pf0 = *(const short8*)&shbuf[((size_t)(pb * 64 + it * 16 + ln)) * 70 + quad * 8];
            const short8 pf1 = *(const short8*)&shbuf[((size_t)(pb * 64 + it * 16 + ln)) * 70 + 32 + quad * 8];
            #pragma unroll
            for (int cc = 0; cc < 4; ++cc) {
                acc[it][cc] = __builtin_amdgcn_mfma_f32_16x16x32_bf16(pf0, vf[cc][0], acc[it][cc], 0, 0, 0);
                acc[it][cc] = __builtin_amdgcn_mfma_f32_16x16x32_bf16(pf1, vf[cc][1], acc[it][cc], 0, 0, 0);
            }
        }
        // ---- rotate prefetched fragments ----
        #pragma unroll
        for (int jc = 0; jc < 4; ++jc) kf[jc] = kf_n[jc];
        #pragma unroll
        for (int cc = 0; cc < 4; ++cc) {
            vf[cc][0] = vf_n[cc][0];
            vf[cc][1] = vf_n[cc][1];
        }
    }

    #pragma unroll
    for (int r = 0; r < 4; ++r) {
        float v = accl[r];
        v += __shfl_xor(v, 1, 16);
        v += __shfl_xor(v, 2, 16);
        v += __shfl_xor(v, 4, 16);
        v += __shfl_xor(v, 8, 16);
        if (ln == 0) lred[w * 16 + quad * 4 + r] = v;
    }
    __syncthreads();   // also orders: last P reads before O_n overwrites shbuf

    // ---- epilogue A: normalize O, write bf16 to LDS [i][c] (stride 266) ----
    #pragma unroll
    for (int it = 0; it < 4; ++it) {
        float linv[4];
        #pragma unroll
        for (int r = 0; r < 4; ++r) linv[r] = 1.f / lred[it * 16 + quad * 4 + r];
        #pragma unroll
        for (int cc = 0; cc < 4; ++cc) {
            const int c = w * 64 + cc * 16 + ln;
            #pragma unroll
            for (int r = 0; r < 4; ++r)
                shbuf[((size_t)(it * 16 + quad * 4 + r)) * 266 + c] = f2b(acc[it][cc][r] * linv[r]);
        }
    }
    __syncthreads();

    // ---- epilogue B: out = Wf * O_n + bf, each wave owns o-chunk w*64 ----
    #pragma unroll
    for (int it = 0; it < 4; ++it) {
        short8 af[8];
        #pragma unroll
        for (int kk = 0; kk < 8; ++kk)
            af[kk] = *(const short8*)&shbuf[((size_t)(it * 16 + ln)) * 266 + kk * 32 + quad * 8];
        #pragma unroll
        for (int oq = 0; oq < 4; ++oq) {
            const int o  = w * 64 + oq * 16 + ln;
            const int og = 20 + w * 4 + oq;
            f32x4 pa = {0.f, 0.f, 0.f, 0.f};
            #pragma unroll
            for (int kk = 0; kk < 8; ++kk) {
                short8 bfr = *(const short8*)(wsw + (size_t)(og * 8 + kk) * 512 + lofs);
                pa = __builtin_amdgcn_mfma_f32_16x16x32_bf16(af[kk], bfr, pa, 0, 0, 0);
            }
            const float bias = bfb[o];
            float4 s = {pa[0] + bias, pa[1] + bias, pa[2] + bias, pa[3] + bias};
            *(float4*)(out + (size_t)(b * 256 + o) * 4096 + i0 + it * 16 + quad * 4) = s;
        }
    }
}

// ---------------------------------------------------------------------------
extern "C" void kernel_launch(void* const* d_in, const int* in_sizes, int n_in,
                              void* d_out, int out_size, void* d_ws, size_t ws_size,
                              hipStream_t stream)
{
    const float* x  = (const float*)d_in[0];
    const float* Wq = (const float*)d_in[1];
    const float* bq = (const float*)d_in[2];
    const float* Wk = (const float*)d_in[3];
    const float* bk = (const float*)d_in[4];
    const float* Wv = (const float*)d_in[5];
    const float* bv = (const float*)d_in[6];
    const float* Wf = (const float*)d_in[7];
    const float* bf = (const float*)d_in[8];
    float* out = (float*)d_out;

    // workspace (shorts): qb, kb, vb, wsw
    unsigned short* qb  = (unsigned short*)d_ws;                  // 8*4096*32
    unsigned short* kb  = qb + (size_t)BATCH * NPOS * CQK;
    unsigned short* vb  = kb + (size_t)BATCH * NPOS * CQK;        // 8*256*4096
    unsigned short* wsw = vb + (size_t)BATCH * CCH * NPOS;        // 36*8*512

    prep_w_kernel<<<36, 256, 0, stream>>>(Wq, Wk, Wv, Wf, wsw);
    qkv_kernel<<<dim3(64, 8), 256, 0, stream>>>(x, wsw, bq, bk, bv, qb, kb, vb);
    attn_kernel<<<512, 256, 0, stream>>>(qb, kb, vb, wsw, bf, out);
}

// Round 5
// 203.854 us; speedup vs baseline: 1.0493x; 1.0041x over previous
//
#include <hip/hip_runtime.h>
#include <hip/hip_bf16.h>

// Problem constants
#define BATCH 8
#define CCH   256
#define NPOS  4096
#define CQK   32

typedef __attribute__((ext_vector_type(8))) short short8;   // 8 bf16 = 4 VGPRs (MFMA A/B frag)
typedef __attribute__((ext_vector_type(4))) float f32x4;    // MFMA C/D frag

__device__ inline unsigned short f2b(float f) {
    __hip_bfloat16 h = __float2bfloat16(f);
    return *reinterpret_cast<unsigned short*>(&h);
}

// ---------------------------------------------------------------------------
// Fragment-block swizzled layouts.  A 512-short block holds one 16x32 MFMA
// operand tile; lane (q=quad, ln) reads short8 at block*512 + (q*16+ln)*8.
//   qb/kb: qk_addr  — [b][n>>4][c>>3][n&15][c&7]           (c < 32)
//   vb:     v_addr  — [b][j>>5][c>>4][(j>>3)&3][c&15][j&7]
//   wsw:    wsw_addr — og-unit = 16 rows x 256 c; og: q=0..1,k=2..3,v=4..19,f=20..35
// ---------------------------------------------------------------------------
__device__ inline size_t qk_addr(int b, int n, int c) {
    return ((((size_t)b * 256 + (n >> 4)) * 4 + (c >> 3)) * 16 + (n & 15)) * 8 + (c & 7);
}
__device__ inline size_t v_addr(int b, int c, int j) {
    return (((((size_t)b * 128 + (j >> 5)) * 16 + (c >> 4)) * 4 + ((j >> 3) & 3)) * 16 + (c & 15)) * 8 + (j & 7);
}
__device__ inline size_t wsw_addr(int og, int c, int ol) {
    return ((size_t)(og * 8 + (c >> 5))) * 512 + (((c >> 3) & 3) * 16 + ol) * 8 + (c & 7);
}

// ---------------------------------------------------------------------------
// Kernel 0: prep_w — weights fp32 -> wsw bf16 fragment layout (36 og units).
// ---------------------------------------------------------------------------
__global__ __launch_bounds__(256, 4)
void prep_w_kernel(const float* __restrict__ Wq, const float* __restrict__ Wk,
                   const float* __restrict__ Wv, const float* __restrict__ Wf,
                   unsigned short* __restrict__ wsw)
{
    const int og = blockIdx.x;           // 0..35
    const int t  = threadIdx.x;
    const float* src; int orow;
    if (og < 2)       { src = Wq; orow = og * 16; }
    else if (og < 4)  { src = Wk; orow = (og - 2) * 16; }
    else if (og < 20) { src = Wv; orow = (og - 4) * 16; }
    else              { src = Wf; orow = (og - 20) * 16; }
    #pragma unroll
    for (int e = 0; e < 16; ++e) {
        int idx = t + e * 256;
        int ol = idx >> 8, c = idx & 255;
        wsw[wsw_addr(og, c, ol)] = f2b(src[(orow + ol) * 256 + c]);
    }
}

// ---------------------------------------------------------------------------
// Kernel 1: fused transpose + QKV projection — R4.
// 512 threads (8 waves); it-loop split across wave halves (per-thread serial
// work halved vs R3).  x staged to LDS TRANSPOSED [n][c] (stride 280 shorts:
// 560B rows -> frag reads are conflict-free ds_read_b128: bank start
// 12*ln+4q mod 32 distinct within 8-lane groups; staging writes bank = c>>1 =
// 2 lanes/bank = free).  Same f2b rounding + MFMA chain order as R3 ->
// bit-identical outputs.
// ---------------------------------------------------------------------------
__global__ __launch_bounds__(512, 2)
void qkv_kernel(const float* __restrict__ x,
                const unsigned short* __restrict__ wsw,
                const float* __restrict__ bq, const float* __restrict__ bk,
                const float* __restrict__ bv,
                unsigned short* __restrict__ qb, unsigned short* __restrict__ kb,
                unsigned short* __restrict__ vb)
{
    __shared__ __align__(16) unsigned short xl[64 * 280];   // [n][c pad 280] = 35840 B

    const int nt   = blockIdx.x;          // 64 position tiles
    const int b    = blockIdx.y;
    const int t    = threadIdx.x;         // 0..511
    const int w    = t >> 6;              // 0..7
    const int lane = t & 63;
    const int q    = lane >> 4;
    const int ln   = lane & 15;
    const int lofs = (q * 16 + ln) * 8;
    const int wq   = w & 3;               // role: 0-1 q, 2-3 k (+ v og chunk)
    const int ith  = w >> 2;              // it-half: waves 0-3 -> it 0,1; 4-7 -> it 2,3

    // ---- stage x tile [256c x 64n] -> bf16 LDS transposed [n][c] ----
    {
        const int c  = t & 255;
        const int nb = (t >> 8) * 4;
        const float* xb = x + ((size_t)(b * 256 + c)) * 4096 + nt * 64;
        #pragma unroll
        for (int e = 0; e < 8; ++e) {
            const int n = nb + e * 8;
            float4 v = *(const float4*)(xb + n);
            xl[(n + 0) * 280 + c] = f2b(v.x);
            xl[(n + 1) * 280 + c] = f2b(v.y);
            xl[(n + 2) * 280 + c] = f2b(v.z);
            xl[(n + 3) * 280 + c] = f2b(v.w);
        }
    }
    __syncthreads();

    // ---- q/k weight fragments (og = wq) + bias ----
    short8 wqk[8];
    #pragma unroll
    for (int kk = 0; kk < 8; ++kk)
        wqk[kk] = *(const short8*)(wsw + (size_t)(wq * 8 + kk) * 512 + lofs);
    const float* bias = (wq < 2) ? bq : bk;
    const int cb16 = (wq & 1) * 16;
    const float b0 = bias[cb16 + q * 4 + 0];
    const float b1 = bias[cb16 + q * 4 + 1];
    const float b2 = bias[cb16 + q * 4 + 2];
    const float b3 = bias[cb16 + q * 4 + 3];
    unsigned short* dst = (wq < 2) ? qb : kb;

    #pragma unroll
    for (int itl = 0; itl < 2; ++itl) {
        const int it = ith * 2 + itl;
        // ---- x^T fragments: vector b128 reads, conflict-free ----
        short8 xf[8];
        #pragma unroll
        for (int kk = 0; kk < 8; ++kk)
            xf[kk] = *(const short8*)&xl[(it * 16 + ln) * 280 + kk * 32 + q * 8];

        // ---- q/k: D[o-rows][n-cols] ----
        {
            f32x4 acc = {b0, b1, b2, b3};
            #pragma unroll
            for (int kk = 0; kk < 8; ++kk)
                acc = __builtin_amdgcn_mfma_f32_16x16x32_bf16(wqk[kk], xf[kk], acc, 0, 0, 0);
            ushort4 s = {f2b(acc[0]), f2b(acc[1]), f2b(acc[2]), f2b(acc[3])};
            *(ushort4*)(dst + qk_addr(b, nt * 64 + it * 16 + ln, cb16 + q * 4)) = s;
        }

        // ---- v: D[j-rows][c-cols], o-chunk wq*64 ----
        #pragma unroll
        for (int oq = 0; oq < 4; ++oq) {
            const int c  = wq * 64 + oq * 16 + ln;
            const float bb = bv[c];
            f32x4 acc = {bb, bb, bb, bb};
            const int og = 4 + wq * 4 + oq;
            #pragma unroll
            for (int kk = 0; kk < 8; ++kk) {
                short8 bfr = *(const short8*)(wsw + (size_t)(og * 8 + kk) * 512 + lofs);
                acc = __builtin_amdgcn_mfma_f32_16x16x32_bf16(xf[kk], bfr, acc, 0, 0, 0);
            }
            ushort4 s = {f2b(acc[0]), f2b(acc[1]), f2b(acc[2]), f2b(acc[3])};
            *(ushort4*)(vb + v_addr(b, c, nt * 64 + it * 16 + q * 4)) = s;
        }
    }
}

// ---------------------------------------------------------------------------
// Kernel 2: fused flash attention + output projection — R4.
// P-write fix: compute S^T via swapped operands mfma(K,Q) so each lane holds
// 4 CONSECUTIVE j per (jc) -> P-writes become ushort4 (b64) instead of 16
// scalar b16 (R0-R3's 4-way write conflict, quad dropped out of the bank).
// P buffer: [2][64][64] shorts + XOR swizzle (byte ^= (ln&7)<<4): b128 reads
// start at bank 4*(quad^(ln&7)) -> conflict-free; writes <=2-way (free).
// Epilogue strides reverted to 264 (R3's 266 BROKE the read tiling: 5ln
// starts overlap; 264 -> 4*(ln+quad) tiles correctly).
// ---------------------------------------------------------------------------
__global__ __launch_bounds__(256, 2)
void attn_kernel(const unsigned short* __restrict__ qb,
                 const unsigned short* __restrict__ kb,
                 const unsigned short* __restrict__ vb,
                 const unsigned short* __restrict__ wsw,
                 const float* __restrict__ bfb, float* __restrict__ out)
{
    // shbuf aliases: main loop P tiles [2][64][64] swizzled (32768 B),
    //                epilogue O_n      [64][264]            (33792 B)
    __shared__ __align__(16) unsigned short shbuf[64 * 264];
    __shared__ float lred[64];

    const int bid  = blockIdx.x;
    const int b    = bid & 7;                    // XCD swizzle
    const int i0   = (bid >> 3) * 64;
    const int t    = threadIdx.x;
    const int w    = t >> 6;
    const int lane = t & 63;
    const int quad = lane >> 4;
    const int ln   = lane & 15;

    const int ibase = i0 + w * 16;
    const int lofs  = (quad * 16 + ln) * 8;
    const unsigned pswz = (unsigned)((ln & 7) << 4);   // P-buffer XOR swizzle

    const short8 qfrag = *(const short8*)(qb + (((size_t)b * 256 + (ibase >> 4)) * 512) + lofs);

    f32x4 acc[4][4];                             // [i-tile][c-chunk]
    #pragma unroll
    for (int it = 0; it < 4; ++it)
        #pragma unroll
        for (int cc = 0; cc < 4; ++cc) acc[it][cc] = (f32x4){0.f, 0.f, 0.f, 0.f};
    float accl = 0.f;                            // row-sum partial for i = w*16+ln

    const unsigned short* kbase = kb + (size_t)b * 256 * 512;
    const unsigned short* vbase = vb + (size_t)b * 128 * 8192;

    // ---- prologue: prefetch j0 = 0 fragments ----
    short8 kf[4], vf[4][2];
    #pragma unroll
    for (int jc = 0; jc < 4; ++jc)
        kf[jc] = *(const short8*)(kbase + (size_t)jc * 512 + lofs);
    #pragma unroll
    for (int cc = 0; cc < 4; ++cc) {
        vf[cc][0] = *(const short8*)(vbase + (w * 4 + cc) * 512 + lofs);
        vf[cc][1] = *(const short8*)(vbase + 8192 + (w * 4 + cc) * 512 + lofs);
    }

    int pb = 0;
    for (int j0 = 0; j0 < 4096; j0 += 64, pb ^= 1) {
        // ---- issue next iteration's K/V loads first (wrap at the end) ----
        const int jn = (j0 + 64) & 4095;
        short8 kf_n[4], vf_n[4][2];
        #pragma unroll
        for (int jc = 0; jc < 4; ++jc)
            kf_n[jc] = *(const short8*)(kbase + ((size_t)((jn >> 4) + jc) * 512) + lofs);
        const unsigned short* vt_n = vbase + (size_t)(jn >> 5) * 8192;
        #pragma unroll
        for (int cc = 0; cc < 4; ++cc) {
            vf_n[cc][0] = *(const short8*)(vt_n + (w * 4 + cc) * 512 + lofs);
            vf_n[cc][1] = *(const short8*)(vt_n + 8192 + (w * 4 + cc) * 512 + lofs);
        }
        // ---- S^T = (Q K^T)^T via swapped operands: lane holds
        //      S[i = w*16+ln][j = jc*16 + quad*4 + r] ----
        f32x4 st[4];
        #pragma unroll
        for (int jc = 0; jc < 4; ++jc)
            st[jc] = __builtin_amdgcn_mfma_f32_16x16x32_bf16(kf[jc], qfrag,
                      (f32x4){0.f, 0.f, 0.f, 0.f}, 0, 0, 0);
        // ---- P = exp(S); row sum; vectorized swizzled P writes ----
        #pragma unroll
        for (int jc = 0; jc < 4; ++jc) {
            float p0 = __expf(st[jc][0]);
            float p1 = __expf(st[jc][1]);
            float p2 = __expf(st[jc][2]);
            float p3 = __expf(st[jc][3]);
            accl += (p0 + p1) + (p2 + p3);
            ushort4 pk = {f2b(p0), f2b(p1), f2b(p2), f2b(p3)};
            unsigned byt = (((unsigned)(pb * 64 + w * 16 + ln)) << 7)
                         + ((jc * 32 + quad * 8) ^ pswz);
            *(ushort4*)((unsigned char*)shbuf + byt) = pk;
        }
        __syncthreads();
        // ---- O += P V with resident V : 32 MFMAs ----
        #pragma unroll
        for (int it = 0; it < 4; ++it) {
            const unsigned rowb = ((unsigned)(pb * 64 + it * 16 + ln)) << 7;
            const short8 pf0 = *(const short8*)((const unsigned char*)shbuf
                                 + rowb + ((quad * 16) ^ pswz));
            const short8 pf1 = *(const short8*)((const unsigned char*)shbuf
                                 + rowb + ((64 + quad * 16) ^ pswz));
            #pragma unroll
            for (int cc = 0; cc < 4; ++cc) {
                acc[it][cc] = __builtin_amdgcn_mfma_f32_16x16x32_bf16(pf0, vf[cc][0], acc[it][cc], 0, 0, 0);
                acc[it][cc] = __builtin_amdgcn_mfma_f32_16x16x32_bf16(pf1, vf[cc][1], acc[it][cc], 0, 0, 0);
            }
        }
        // ---- rotate prefetched fragments ----
        #pragma unroll
        for (int jc = 0; jc < 4; ++jc) kf[jc] = kf_n[jc];
        #pragma unroll
        for (int cc = 0; cc < 4; ++cc) {
            vf[cc][0] = vf_n[cc][0];
            vf[cc][1] = vf_n[cc][1];
        }
    }

    // ---- row sums: accl holds partial for row i = w*16+ln; reduce quads ----
    {
        float v = accl;
        v += __shfl_xor(v, 16, 64);
        v += __shfl_xor(v, 32, 64);
        if (lane < 16) lred[w * 16 + lane] = v;
    }
    __syncthreads();   // also orders: last P reads before O_n overwrites shbuf

    // ---- epilogue A: normalize O, write bf16 to LDS [i][c] (stride 264) ----
    #pragma unroll
    for (int it = 0; it < 4; ++it) {
        float linv[4];
        #pragma unroll
        for (int r = 0; r < 4; ++r) linv[r] = 1.f / lred[it * 16 + quad * 4 + r];
        #pragma unroll
        for (int cc = 0; cc < 4; ++cc) {
            const int c = w * 64 + cc * 16 + ln;
            #pragma unroll
            for (int r = 0; r < 4; ++r)
                shbuf[((size_t)(it * 16 + quad * 4 + r)) * 264 + c] = f2b(acc[it][cc][r] * linv[r]);
        }
    }
    __syncthreads();

    // ---- epilogue B: out = Wf * O_n + bf, each wave owns o-chunk w*64 ----
    #pragma unroll
    for (int it = 0; it < 4; ++it) {
        short8 af[8];
        #pragma unroll
        for (int kk = 0; kk < 8; ++kk)
            af[kk] = *(const short8*)&shbuf[((size_t)(it * 16 + ln)) * 264 + kk * 32 + quad * 8];
        #pragma unroll
        for (int oq = 0; oq < 4; ++oq) {
            const int o  = w * 64 + oq * 16 + ln;
            const int og = 20 + w * 4 + oq;
            f32x4 pa = {0.f, 0.f, 0.f, 0.f};
            #pragma unroll
            for (int kk = 0; kk < 8; ++kk) {
                short8 bfr = *(const short8*)(wsw + (size_t)(og * 8 + kk) * 512 + lofs);
                pa = __builtin_amdgcn_mfma_f32_16x16x32_bf16(af[kk], bfr, pa, 0, 0, 0);
            }
            const float bias = bfb[o];
            float4 s = {pa[0] + bias, pa[1] + bias, pa[2] + bias, pa[3] + bias};
            *(float4*)(out + (size_t)(b * 256 + o) * 4096 + i0 + it * 16 + quad * 4) = s;
        }
    }
}

// ---------------------------------------------------------------------------
extern "C" void kernel_launch(void* const* d_in, const int* in_sizes, int n_in,
                              void* d_out, int out_size, void* d_ws, size_t ws_size,
                              hipStream_t stream)
{
    const float* x  = (const float*)d_in[0];
    const float* Wq = (const float*)d_in[1];
    const float* bq = (const float*)d_in[2];
    const float* Wk = (const float*)d_in[3];
    const float* bk = (const float*)d_in[4];
    const float* Wv = (const float*)d_in[5];
    const float* bv = (const float*)d_in[6];
    const float* Wf = (const float*)d_in[7];
    const float* bf = (const float*)d_in[8];
    float* out = (float*)d_out;

    // workspace (shorts): qb, kb, vb, wsw
    unsigned short* qb  = (unsigned short*)d_ws;                  // 8*4096*32
    unsigned short* kb  = qb + (size_t)BATCH * NPOS * CQK;
    unsigned short* vb  = kb + (size_t)BATCH * NPOS * CQK;        // 8*256*4096
    unsigned short* wsw = vb + (size_t)BATCH * CCH * NPOS;        // 36*8*512

    prep_w_kernel<<<36, 256, 0, stream>>>(Wq, Wk, Wv, Wf, wsw);
    qkv_kernel<<<dim3(64, 8), 512, 0, stream>>>(x, wsw, bq, bk, bv, qb, kb, vb);
    attn_kernel<<<512, 256, 0, stream>>>(qb, kb, vb, wsw, bf, out);
}